// Round 1
// baseline (897.254 us; speedup 1.0000x reference)
//
#include <hip/hip_runtime.h>
#include <hip/hip_bf16.h>

#define LL 1024
#define BB 256
#define CC 96
#define HH 768

// ---------------- GEMM: out[m][n] = sum_k A[m][k]*W[n][k] + bias[n] ----------
// M=256 fixed, K=768 fixed, N variable (9216 or 96).
#define MT 64
#define NT 128
#define KT 16
#define LDT 20  // padded LDS row stride (dwords): 20%32=4 -> conflict-light, 80B row = 16B aligned

__global__ __launch_bounds__(256) void gemm_k(const float* __restrict__ A,
                                              const float* __restrict__ W,
                                              const float* __restrict__ bias,
                                              float* __restrict__ out, int N) {
  __shared__ __align__(16) float As[MT * LDT];
  __shared__ __align__(16) float Bs[NT * LDT];
  const int t = threadIdx.x;
  const int m0 = blockIdx.y * MT;
  const int n0 = blockIdx.x * NT;
  const int tx = t & 15;   // n micro index
  const int ty = t >> 4;   // m micro index
  float acc[4][8];
#pragma unroll
  for (int i = 0; i < 4; ++i)
#pragma unroll
    for (int j = 0; j < 8; ++j) acc[i][j] = 0.f;

  const int arow = t >> 2;
  const int ak4 = (t & 3) * 4;

  for (int k0 = 0; k0 < HH; k0 += KT) {
    __syncthreads();
    // A tile: 64 rows x 16 k (one float4 per thread), stored [m][k]
    {
      float4 v = *(const float4*)&A[(m0 + arow) * HH + k0 + ak4];
      *(float4*)&As[arow * LDT + ak4] = v;
    }
    // B tile: 128 rows x 16 k (two float4 per thread)
#pragma unroll
    for (int r = 0; r < 2; ++r) {
      int f = t + r * 256;
      int row = f >> 2, k4 = (f & 3) * 4;
      float4 v = make_float4(0.f, 0.f, 0.f, 0.f);
      if (n0 + row < N) v = *(const float4*)&W[(n0 + row) * HH + k0 + k4];
      *(float4*)&Bs[row * LDT + k4] = v;
    }
    __syncthreads();
#pragma unroll
    for (int kk = 0; kk < KT; kk += 4) {
      float4 a4[4], b4[8];
#pragma unroll
      for (int i = 0; i < 4; ++i) a4[i] = *(const float4*)&As[(ty + 16 * i) * LDT + kk];
#pragma unroll
      for (int j = 0; j < 8; ++j) b4[j] = *(const float4*)&Bs[(tx + 16 * j) * LDT + kk];
#pragma unroll
      for (int i = 0; i < 4; ++i)
#pragma unroll
        for (int j = 0; j < 8; ++j) {
          acc[i][j] += a4[i].x * b4[j].x + a4[i].y * b4[j].y +
                       a4[i].z * b4[j].z + a4[i].w * b4[j].w;
        }
    }
  }
#pragma unroll
  for (int j = 0; j < 8; ++j) {
    int n = n0 + tx + 16 * j;
    if (n < N) {
      float bv = bias[n];
#pragma unroll
      for (int i = 0; i < 4; ++i) {
        int m = m0 + ty + 16 * i;
        out[m * N + n] = acc[i][j] + bv;
      }
    }
  }
}

// ---------------- CRF scan: one block per batch element ----------------------
#define NTH 384
#define CHUNK 32

__global__ __launch_bounds__(384) void crf_scan(
    const float* __restrict__ emit, const int* __restrict__ target,
    const void* __restrict__ mask, const float* __restrict__ trans,
    const float* __restrict__ tstart, const float* __restrict__ tend,
    float* __restrict__ out) {
  const int b = blockIdx.x;
  const int t = threadIdx.x;
  const int c = t % 96;  // state column this thread owns
  const int h = t / 96;  // quarter of the c' (previous-state) range

  __shared__ __align__(16) float p_lds[96];            // exp(shifted alpha)
  __shared__ float part[4 * 96];                       // dot partials
  __shared__ __align__(16) float ebuf[2 * CHUNK * 96]; // emit ring buffer
  __shared__ float red[512];
  __shared__ int len_sh;
  __shared__ float logz_sh;

  // ---- sequence length from mask (dtype sniffed at runtime) ----
  {
    unsigned w0 = *(const unsigned*)mask;
    int cnt = 0;
    if (w0 == 1u) {  // int32 layout
      const int* m32 = (const int*)mask;
      for (int i = t; i < LL; i += NTH) cnt += (m32[i * BB + b] != 0);
    } else if (w0 == 0x01010101u) {  // byte/bool layout
      const unsigned char* m8 = (const unsigned char*)mask;
      for (int i = t; i < LL; i += NTH) cnt += (m8[i * BB + b] != 0);
    } else {  // float layout
      const float* mf = (const float*)mask;
      for (int i = t; i < LL; i += NTH) cnt += (mf[i * BB + b] != 0.f);
    }
    red[t] = (float)cnt;
    if (t < 128) red[384 + t] = 0.f;
    __syncthreads();
    for (int s = 256; s >= 1; s >>= 1) {
      if (t < s) red[t] += red[t + s];
      __syncthreads();
    }
    if (t == 0) len_sh = (int)(red[0] + 0.5f);
    __syncthreads();
  }
  const int len = len_sh;

  // ---- T = exp(trans[b]) into registers: thread owns T[24h..24h+23][c] ----
  const float* tb = trans + (long)b * (96 * 96);
  float Treg[24];
#pragma unroll
  for (int j = 0; j < 24; ++j) Treg[j] = __expf(tb[(h * 24 + j) * 96 + c]);

  // ---- emit chunk prefetch pipeline ----
  const int rw = t / 24;              // row-in-chunk (0..15), +16 for second
  const int c4 = t % 24;              // float4 column
  const float4* e4 = (const float4*)emit;
  float4 r0, r1;
  // chunk 0 -> LDS now
  r0 = e4[((0 + rw) * BB + b) * 24 + c4];
  r1 = e4[((16 + rw) * BB + b) * 24 + c4];
  *(float4*)&ebuf[(0 * CHUNK + rw) * 96 + c4 * 4] = r0;
  *(float4*)&ebuf[(0 * CHUNK + rw + 16) * 96 + c4 * 4] = r1;
  // chunk 1 -> regs (held until i hits 32)
  r0 = e4[((CHUNK + rw) * BB + b) * 24 + c4];
  r1 = e4[((CHUNK + rw + 16) * BB + b) * 24 + c4];

  // ---- init: log_alpha0 = emit[0] + t_start, pivot on column 0 ----
  float a_reg = 0.f, S = 0.f;
  if (t < 96) {
    float v = emit[(long)b * CC + c] + tstart[b * 96 + c];
    float v0 = emit[(long)b * CC + 0] + tstart[b * 96 + 0];
    a_reg = v - v0;
    S = v0;
    p_lds[c] = __expf(a_reg);
  }
  __syncthreads();

  // ---- main recurrence ----
  for (int i = 1; i < len; ++i) {
    if ((i & 31) == 0) {
      int ch = i >> 5;
      int slot = ch & 1;
      *(float4*)&ebuf[(slot * CHUNK + rw) * 96 + c4 * 4] = r0;
      *(float4*)&ebuf[(slot * CHUNK + rw + 16) * 96 + c4 * 4] = r1;
      __syncthreads();
      int nb = (ch + 1) * CHUNK;
      if (nb < LL) {
        r0 = e4[((nb + rw) * BB + b) * 24 + c4];
        r1 = e4[((nb + rw + 16) * BB + b) * 24 + c4];
      }
    }
    // dot: d[c] partial over this thread's 24 previous states
    float accd = 0.f;
    const float4* p4 = (const float4*)p_lds;
#pragma unroll
    for (int j = 0; j < 6; ++j) {
      float4 pv = p4[h * 6 + j];  // wave-broadcast read
      accd += pv.x * Treg[4 * j + 0] + pv.y * Treg[4 * j + 1] +
              pv.z * Treg[4 * j + 2] + pv.w * Treg[4 * j + 3];
    }
    part[t] = accd;
    __syncthreads();
    if (t < 96) {
      float d = part[c] + part[96 + c] + part[192 + c] + part[288 + c];
      float d0 = part[0] + part[96] + part[192] + part[288];  // broadcast
      int slot = (i >> 5) & 1, ir = i & 31;
      float e_c = ebuf[(slot * CHUNK + ir) * 96 + c];
      float e_0 = ebuf[(slot * CHUNK + ir) * 96 + 0];
      float val = e_c + __logf(d);     // new log_alpha[c] - S
      float val0 = e_0 + __logf(d0);   // pivot (value at c==0)
      a_reg = val - val0;              // a[0] == 0 exactly -> no under/overflow
      S += val0;
      p_lds[c] = __expf(a_reg);
    }
    __syncthreads();
  }

  // ---- log Z for this batch ----
  if (t < 96) red[t] = a_reg + tend[b * 96 + c];
  __syncthreads();
  if (t == 0) {
    float m = -1e30f;
    for (int k = 0; k < 96; ++k) m = fmaxf(m, red[k]);
    float sum = 0.f;
    for (int k = 0; k < 96; ++k) sum += __expf(red[k] - m);
    logz_sh = S + m + __logf(sum);
  }
  __syncthreads();

  // ---- gold-path score ----
  float sc = 0.f;
  for (int i = t; i < len; i += NTH) {
    int tg = target[i * BB + b];
    sc += emit[((long)i * BB + b) * CC + tg];
    if (i >= 1) {
      int tp = target[(i - 1) * BB + b];
      sc += tb[tp * 96 + tg];
    }
  }
  red[t] = sc;
  if (t < 128) red[384 + t] = 0.f;
  __syncthreads();
  for (int s = 256; s >= 1; s >>= 1) {
    if (t < s) red[t] += red[t + s];
    __syncthreads();
  }
  if (t == 0) {
    int tg0 = target[b];
    int tgl = target[(len - 1) * BB + b];
    float score = red[0] + tstart[b * 96 + tg0] + tend[b * 96 + tgl];
    atomicAdd(out, (logz_sh - score) * (1.0f / 256.0f));
  }
}

extern "C" void kernel_launch(void* const* d_in, const int* in_sizes, int n_in,
                              void* d_out, int out_size, void* d_ws, size_t ws_size,
                              hipStream_t stream) {
  const float* emit = (const float*)d_in[0];
  const float* hidden = (const float*)d_in[1];
  const int* target = (const int*)d_in[2];
  const void* mask = d_in[3];
  const float* Wt = (const float*)d_in[4];
  const float* bt = (const float*)d_in[5];
  const float* Ws = (const float*)d_in[6];
  const float* bs = (const float*)d_in[7];
  const float* We = (const float*)d_in[8];
  const float* be = (const float*)d_in[9];

  float* trans_ws = (float*)d_ws;                       // 256*9216
  float* ts_ws = trans_ws + (size_t)BB * CC * CC;       // 256*96
  float* te_ws = ts_ws + (size_t)BB * CC;               // 256*96

  hipMemsetAsync(d_out, 0, sizeof(float), stream);

  gemm_k<<<dim3((CC * CC + NT - 1) / NT, BB / MT), 256, 0, stream>>>(
      hidden, Wt, bt, trans_ws, CC * CC);
  gemm_k<<<dim3(1, BB / MT), 256, 0, stream>>>(hidden, Ws, bs, ts_ws, CC);
  gemm_k<<<dim3(1, BB / MT), 256, 0, stream>>>(hidden, We, be, te_ws, CC);

  crf_scan<<<BB, NTH, 0, stream>>>(emit, target, mask, trans_ws, ts_ws, te_ws,
                                   (float*)d_out);
}

// Round 2
// 581.366 us; speedup vs baseline: 1.5434x; 1.5434x over previous
//
#include <hip/hip_runtime.h>
#include <hip/hip_bf16.h>
#include <stdint.h>

#define LL 1024
#define BB 256
#define CC 96
#define HH 768
#define NW 9216   // CC*CC
#define NTOT 9408 // NW + 2*CC

typedef __attribute__((ext_vector_type(4))) float floatx4;
typedef __attribute__((ext_vector_type(8))) short short8;

#define KAPPA 0x1p-16f
#define NEG_LOG_KAPPA 11.090354888959125f  // 16*ln2

__device__ __forceinline__ unsigned short f2bf(float f) {
  uint32_t u = __float_as_uint(f);
  return (unsigned short)((u + 0x7FFFu + ((u >> 16) & 1u)) >> 16);
}

// ---------------- fused bf16 MFMA GEMM: out = hidden @ [Wt;Ws;We]^T + bias ---
#define GA_LD 40  // ushort row stride: 80 B -> 2-way-max LDS conflicts (free)

__global__ __launch_bounds__(256) void gemm_mfma(
    const float* __restrict__ hidden, const float* __restrict__ Wt,
    const float* __restrict__ Ws, const float* __restrict__ We,
    const float* __restrict__ bt, const float* __restrict__ bs,
    const float* __restrict__ be, float* __restrict__ trans,
    float* __restrict__ tstart, float* __restrict__ tend) {
  __shared__ __align__(16) unsigned short As[128 * GA_LD];
  __shared__ __align__(16) unsigned short Bs[128 * GA_LD];
  const int t = threadIdx.x;
  const int lane = t & 63, wid = t >> 6;
  const int wm = wid >> 1, wn = wid & 1;
  const int l15 = lane & 15, qd = lane >> 4;
  const int m0 = blockIdx.y * 128, n0 = blockIdx.x * 128;
  const int srow = t >> 1, shalf = t & 1;

  floatx4 acc[4][4];
#pragma unroll
  for (int i = 0; i < 4; ++i)
#pragma unroll
    for (int j = 0; j < 4; ++j) acc[i][j] = (floatx4){0.f, 0.f, 0.f, 0.f};

  const int r = n0 + srow;
  const float* bsrc = (r < NW)        ? Wt + (size_t)r * HH
                      : (r < NW + CC) ? Ws + (size_t)(r - NW) * HH
                      : (r < NTOT)    ? We + (size_t)(r - NW - CC) * HH
                                      : nullptr;
  const float* asrc = hidden + (size_t)(m0 + srow) * HH;
  const int sidx = srow * GA_LD + shalf * 16;

  for (int k0 = 0; k0 < HH; k0 += 32) {
    __syncthreads();
    {  // stage A (fp32 -> bf16)
      const float4* s4 = (const float4*)(asrc + k0 + shalf * 16);
      uint32_t w[8];
#pragma unroll
      for (int u = 0; u < 4; ++u) {
        float4 v = s4[u];
        w[2 * u] = (uint32_t)f2bf(v.x) | ((uint32_t)f2bf(v.y) << 16);
        w[2 * u + 1] = (uint32_t)f2bf(v.z) | ((uint32_t)f2bf(v.w) << 16);
      }
      *(uint4*)&As[sidx] = make_uint4(w[0], w[1], w[2], w[3]);
      *(uint4*)&As[sidx + 8] = make_uint4(w[4], w[5], w[6], w[7]);
    }
    {  // stage B (fused row source)
      uint32_t w[8];
      if (bsrc) {
        const float4* s4 = (const float4*)(bsrc + k0 + shalf * 16);
#pragma unroll
        for (int u = 0; u < 4; ++u) {
          float4 v = s4[u];
          w[2 * u] = (uint32_t)f2bf(v.x) | ((uint32_t)f2bf(v.y) << 16);
          w[2 * u + 1] = (uint32_t)f2bf(v.z) | ((uint32_t)f2bf(v.w) << 16);
        }
      } else {
#pragma unroll
        for (int u = 0; u < 8; ++u) w[u] = 0u;
      }
      *(uint4*)&Bs[sidx] = make_uint4(w[0], w[1], w[2], w[3]);
      *(uint4*)&Bs[sidx + 8] = make_uint4(w[4], w[5], w[6], w[7]);
    }
    __syncthreads();
    short8 af[4], bf[4];
#pragma unroll
    for (int i = 0; i < 4; ++i)
      af[i] = *(const short8*)&As[(64 * wm + 16 * i + l15) * GA_LD + qd * 8];
#pragma unroll
    for (int j = 0; j < 4; ++j)
      bf[j] = *(const short8*)&Bs[(64 * wn + 16 * j + l15) * GA_LD + qd * 8];
#pragma unroll
    for (int i = 0; i < 4; ++i)
#pragma unroll
      for (int j = 0; j < 4; ++j)
        acc[i][j] = __builtin_amdgcn_mfma_f32_16x16x32_bf16(af[i], bf[j],
                                                            acc[i][j], 0, 0, 0);
  }

#pragma unroll
  for (int j = 0; j < 4; ++j) {
    int n = n0 + 64 * wn + 16 * j + l15;
    if (n >= NTOT) continue;
    float bv;
    float* dst;
    int ldo;
    if (n < NW) {
      bv = bt[n]; dst = trans + n; ldo = NW;
    } else if (n < NW + CC) {
      bv = bs[n - NW]; dst = tstart + (n - NW); ldo = CC;
    } else {
      bv = be[n - NW - CC]; dst = tend + (n - NW - CC); ldo = CC;
    }
#pragma unroll
    for (int i = 0; i < 4; ++i)
#pragma unroll
      for (int rr = 0; rr < 4; ++rr) {
        int m = m0 + 64 * wm + 16 * i + 4 * qd + rr;
        dst[(size_t)m * ldo] = acc[i][j][rr] + bv;
      }
  }
}

// ---------------- CRF scan: exp-domain, stale-pivot renorm, 1 barrier/step --
#define NTH 384
#define CHUNK 32

__device__ __forceinline__ void estore(float* dst, float4 v) {
  float4 o;
  o.x = __expf(v.x) * KAPPA;
  o.y = __expf(v.y) * KAPPA;
  o.z = __expf(v.z) * KAPPA;
  o.w = __expf(v.w) * KAPPA;
  *(float4*)dst = o;
}

__global__ __launch_bounds__(384) void crf_scan(
    const float* __restrict__ emit, const int* __restrict__ target,
    const void* __restrict__ mask, const float* __restrict__ trans,
    const float* __restrict__ tstart, const float* __restrict__ tend,
    float* __restrict__ out) {
  const int b = blockIdx.x;
  const int t = threadIdx.x;
  const int c = t >> 2;  // state (0..95)
  const int q = t & 3;   // quarter of previous-state range

  __shared__ __align__(16) float p_lds[2][CC];         // scaled alpha (exp dom)
  __shared__ __align__(16) float ebuf[2 * CHUNK * CC]; // exp(emit)*kappa ring
  __shared__ float red[512];
  __shared__ int len_sh;
  __shared__ float logz_sh;

  // ---- sequence length from mask (dtype sniffed at runtime) ----
  {
    unsigned w0 = *(const unsigned*)mask;
    int cnt = 0;
    if (w0 == 1u) {
      const int* m32 = (const int*)mask;
      for (int i = t; i < LL; i += NTH) cnt += (m32[i * BB + b] != 0);
    } else if (w0 == 0x01010101u) {
      const unsigned char* m8 = (const unsigned char*)mask;
      for (int i = t; i < LL; i += NTH) cnt += (m8[i * BB + b] != 0);
    } else {
      const float* mf = (const float*)mask;
      for (int i = t; i < LL; i += NTH) cnt += (mf[i * BB + b] != 0.f);
    }
    red[t] = (float)cnt;
    if (t < 128) red[384 + t] = 0.f;
    __syncthreads();
    for (int s = 256; s >= 1; s >>= 1) {
      if (t < s) red[t] += red[t + s];
      __syncthreads();
    }
    if (t == 0) len_sh = (int)(red[0] + 0.5f);
    __syncthreads();
  }
  const int len = len_sh;

  // ---- T = exp(trans): thread (c,q) owns rows 24q..24q+23 of column c ----
  const float* tb = trans + (size_t)b * (CC * CC);
  float Treg[24];
#pragma unroll
  for (int j = 0; j < 24; ++j) Treg[j] = __expf(tb[(q * 24 + j) * CC + c]);

  // ---- emit chunk prefetch pipeline (stores exp(emit)*kappa) ----
  const int rw = t / 24;
  const int c4 = t % 24;
  const float4* e4 = (const float4*)emit;
  float4 r0, r1;
  r0 = e4[((0 + rw) * BB + b) * 24 + c4];
  r1 = e4[((16 + rw) * BB + b) * 24 + c4];
  estore(&ebuf[(0 * CHUNK + rw) * CC + c4 * 4], r0);
  estore(&ebuf[(0 * CHUNK + rw + 16) * CC + c4 * 4], r1);
  r0 = e4[((CHUNK + rw) * BB + b) * 24 + c4];
  r1 = e4[((CHUNK + rw + 16) * BB + b) * 24 + c4];

  // ---- init: u0 = exp(a0 - a0[0]), L = a0[0] ----
  float a00 = emit[(size_t)b * CC] + tstart[b * CC];
  float L = a00;
  if (t < CC) {
    float v = emit[(size_t)b * CC + t] + tstart[b * CC + t];
    p_lds[0][t] = __expf(v - a00);
  }
  __syncthreads();

  // ---- main recurrence: one barrier per step ----
  for (int i = 1; i < len; ++i) {
    if ((i & 31) == 0) {
      int ch = i >> 5;
      int es = ch & 1;
      estore(&ebuf[(es * CHUNK + rw) * CC + c4 * 4], r0);
      estore(&ebuf[(es * CHUNK + rw + 16) * CC + c4 * 4], r1);
      __syncthreads();
      int nb = (ch + 1) * CHUNK;
      if (nb < LL) {
        r0 = e4[((nb + rw) * BB + b) * 24 + c4];
        r1 = e4[((nb + rw + 16) * BB + b) * 24 + c4];
      }
    }
    const int slot_r = (i + 1) & 1;
    const float4* p4 = (const float4*)&p_lds[slot_r][0];
    float piv = p_lds[slot_r][0];  // broadcast read; stale pivot
    float inv = 1.0f / piv;
    float acc = 0.f;
#pragma unroll
    for (int j = 0; j < 6; ++j) {
      float4 pv = p4[q * 6 + j];
      acc += pv.x * Treg[4 * j + 0] + pv.y * Treg[4 * j + 1] +
             pv.z * Treg[4 * j + 2] + pv.w * Treg[4 * j + 3];
    }
    acc += __shfl_xor(acc, 1);
    acc += __shfl_xor(acc, 2);
    float E = ebuf[(((i >> 5) & 1) * CHUNK + (i & 31)) * CC + c];
    if (q == 0) p_lds[i & 1][c] = acc * E * inv;
    L += __logf(piv);  // off-chain scale tracking (redundant per thread)
    __syncthreads();
  }

  // ---- log Z ----
  const int fs = (len - 1) & 1;
  red[t] = (t < CC) ? p_lds[fs][t] * __expf(tend[b * CC + t]) : 0.f;
  if (t < 128) red[384 + t] = 0.f;
  __syncthreads();
  for (int s = 256; s >= 1; s >>= 1) {
    if (t < s) red[t] += red[t + s];
    __syncthreads();
  }
  if (t == 0)
    logz_sh = L + (float)(len - 1) * NEG_LOG_KAPPA + __logf(red[0]);
  __syncthreads();

  // ---- gold-path score ----
  float sc = 0.f;
  for (int i = t; i < len; i += NTH) {
    int tg = target[i * BB + b];
    sc += emit[((size_t)i * BB + b) * CC + tg];
    if (i >= 1) {
      int tp = target[(i - 1) * BB + b];
      sc += tb[tp * CC + tg];
    }
  }
  red[t] = sc;
  if (t < 128) red[384 + t] = 0.f;
  __syncthreads();
  for (int s = 256; s >= 1; s >>= 1) {
    if (t < s) red[t] += red[t + s];
    __syncthreads();
  }
  if (t == 0) {
    int tg0 = target[b];
    int tgl = target[(len - 1) * BB + b];
    float score = red[0] + tstart[b * CC + tg0] + tend[b * CC + tgl];
    atomicAdd(out, (logz_sh - score) * (1.0f / 256.0f));
  }
}

extern "C" void kernel_launch(void* const* d_in, const int* in_sizes, int n_in,
                              void* d_out, int out_size, void* d_ws, size_t ws_size,
                              hipStream_t stream) {
  const float* emit = (const float*)d_in[0];
  const float* hidden = (const float*)d_in[1];
  const int* target = (const int*)d_in[2];
  const void* mask = d_in[3];
  const float* Wt = (const float*)d_in[4];
  const float* bt = (const float*)d_in[5];
  const float* Ws = (const float*)d_in[6];
  const float* bs = (const float*)d_in[7];
  const float* We = (const float*)d_in[8];
  const float* be = (const float*)d_in[9];

  float* trans_ws = (float*)d_ws;                  // 256*9216
  float* ts_ws = trans_ws + (size_t)BB * CC * CC;  // 256*96
  float* te_ws = ts_ws + (size_t)BB * CC;          // 256*96

  hipMemsetAsync(d_out, 0, sizeof(float), stream);

  gemm_mfma<<<dim3((NTOT + 127) / 128, 2), 256, 0, stream>>>(
      hidden, Wt, Ws, We, bt, bs, be, trans_ws, ts_ws, te_ws);

  crf_scan<<<BB, NTH, 0, stream>>>(emit, target, mask, trans_ws, ts_ws, te_ws,
                                   (float*)d_out);
}

// Round 3
// 573.022 us; speedup vs baseline: 1.5658x; 1.0146x over previous
//
#include <hip/hip_runtime.h>
#include <hip/hip_bf16.h>
#include <stdint.h>

#define LL 1024
#define BB 256
#define CC 96
#define HH 768
#define NW 9216   // CC*CC
#define NTOT 9408 // NW + 2*CC

typedef __attribute__((ext_vector_type(4))) float floatx4;
typedef __attribute__((ext_vector_type(8))) short short8;

#define KAPPA 0x1p-16f
#define NEG_LOG_KAPPA 11.090354888959125f  // 16*ln2

__device__ __forceinline__ unsigned short f2bf(float f) {
  uint32_t u = __float_as_uint(f);
  return (unsigned short)((u + 0x7FFFu + ((u >> 16) & 1u)) >> 16);
}

// ---------------- fused bf16 MFMA GEMM: out = hidden @ [Wt;Ws;We]^T + bias ---
#define GA_LD 40  // ushort row stride: 80 B -> 2-way-max LDS conflicts (free)

__global__ __launch_bounds__(256) void gemm_mfma(
    const float* __restrict__ hidden, const float* __restrict__ Wt,
    const float* __restrict__ Ws, const float* __restrict__ We,
    const float* __restrict__ bt, const float* __restrict__ bs,
    const float* __restrict__ be, float* __restrict__ trans,
    float* __restrict__ tstart, float* __restrict__ tend) {
  __shared__ __align__(16) unsigned short As[128 * GA_LD];
  __shared__ __align__(16) unsigned short Bs[128 * GA_LD];
  const int t = threadIdx.x;
  const int lane = t & 63, wid = t >> 6;
  const int wm = wid >> 1, wn = wid & 1;
  const int l15 = lane & 15, qd = lane >> 4;
  const int m0 = blockIdx.y * 128, n0 = blockIdx.x * 128;
  const int srow = t >> 1, shalf = t & 1;

  floatx4 acc[4][4];
#pragma unroll
  for (int i = 0; i < 4; ++i)
#pragma unroll
    for (int j = 0; j < 4; ++j) acc[i][j] = (floatx4){0.f, 0.f, 0.f, 0.f};

  const int r = n0 + srow;
  const float* bsrc = (r < NW)        ? Wt + (size_t)r * HH
                      : (r < NW + CC) ? Ws + (size_t)(r - NW) * HH
                      : (r < NTOT)    ? We + (size_t)(r - NW - CC) * HH
                                      : nullptr;
  const float* asrc = hidden + (size_t)(m0 + srow) * HH;
  const int sidx = srow * GA_LD + shalf * 16;

  for (int k0 = 0; k0 < HH; k0 += 32) {
    __syncthreads();
    {  // stage A (fp32 -> bf16)
      const float4* s4 = (const float4*)(asrc + k0 + shalf * 16);
      uint32_t w[8];
#pragma unroll
      for (int u = 0; u < 4; ++u) {
        float4 v = s4[u];
        w[2 * u] = (uint32_t)f2bf(v.x) | ((uint32_t)f2bf(v.y) << 16);
        w[2 * u + 1] = (uint32_t)f2bf(v.z) | ((uint32_t)f2bf(v.w) << 16);
      }
      *(uint4*)&As[sidx] = make_uint4(w[0], w[1], w[2], w[3]);
      *(uint4*)&As[sidx + 8] = make_uint4(w[4], w[5], w[6], w[7]);
    }
    {  // stage B (fused row source)
      uint32_t w[8];
      if (bsrc) {
        const float4* s4 = (const float4*)(bsrc + k0 + shalf * 16);
#pragma unroll
        for (int u = 0; u < 4; ++u) {
          float4 v = s4[u];
          w[2 * u] = (uint32_t)f2bf(v.x) | ((uint32_t)f2bf(v.y) << 16);
          w[2 * u + 1] = (uint32_t)f2bf(v.z) | ((uint32_t)f2bf(v.w) << 16);
        }
      } else {
#pragma unroll
        for (int u = 0; u < 8; ++u) w[u] = 0u;
      }
      *(uint4*)&Bs[sidx] = make_uint4(w[0], w[1], w[2], w[3]);
      *(uint4*)&Bs[sidx + 8] = make_uint4(w[4], w[5], w[6], w[7]);
    }
    __syncthreads();
    short8 af[4], bf[4];
#pragma unroll
    for (int i = 0; i < 4; ++i)
      af[i] = *(const short8*)&As[(64 * wm + 16 * i + l15) * GA_LD + qd * 8];
#pragma unroll
    for (int j = 0; j < 4; ++j)
      bf[j] = *(const short8*)&Bs[(64 * wn + 16 * j + l15) * GA_LD + qd * 8];
#pragma unroll
    for (int i = 0; i < 4; ++i)
#pragma unroll
      for (int j = 0; j < 4; ++j)
        acc[i][j] = __builtin_amdgcn_mfma_f32_16x16x32_bf16(af[i], bf[j],
                                                            acc[i][j], 0, 0, 0);
  }

#pragma unroll
  for (int j = 0; j < 4; ++j) {
    int n = n0 + 64 * wn + 16 * j + l15;
    if (n >= NTOT) continue;
    float bv;
    float* dst;
    int ldo;
    if (n < NW) {
      bv = bt[n]; dst = trans + n; ldo = NW;
    } else if (n < NW + CC) {
      bv = bs[n - NW]; dst = tstart + (n - NW); ldo = CC;
    } else {
      bv = be[n - NW - CC]; dst = tend + (n - NW - CC); ldo = CC;
    }
#pragma unroll
    for (int i = 0; i < 4; ++i)
#pragma unroll
      for (int rr = 0; rr < 4; ++rr) {
        int m = m0 + 64 * wm + 16 * i + 4 * qd + rr;
        dst[(size_t)m * ldo] = acc[i][j][rr] + bv;
      }
  }
}

// ------- CRF scan v3: 192 thr, 2 states/lane, renorm every 4 steps ---------
#define NTH 192
#define CHUNK 32

__global__ __launch_bounds__(192) void crf_scan(
    const float* __restrict__ emit, const int* __restrict__ target,
    const void* __restrict__ mask, const float* __restrict__ trans,
    const float* __restrict__ tstart, const float* __restrict__ tend,
    float* __restrict__ out) {
  const int b = blockIdx.x;
  const int t = threadIdx.x;
  const int q = t & 3;   // slice of previous-state range (24 each)
  const int p = t >> 2;  // state pair (0..47): owns states 2p, 2p+1

  __shared__ __align__(16) float p_lds[2][CC];          // unnormalized alpha (exp dom)
  __shared__ __align__(16) float ebuf[2][CHUNK][CC];    // exp(emit)*kappa ring
  __shared__ float red[256];
  __shared__ int len_sh;
  __shared__ float logz_sh;

  // ---- sequence length from mask (dtype sniffed at runtime) ----
  {
    unsigned w0 = *(const unsigned*)mask;
    int cnt = 0;
    if (w0 == 1u) {
      const int* m32 = (const int*)mask;
      for (int i = t; i < LL; i += NTH) cnt += (m32[i * BB + b] != 0);
    } else if (w0 == 0x01010101u) {
      const unsigned char* m8 = (const unsigned char*)mask;
      for (int i = t; i < LL; i += NTH) cnt += (m8[i * BB + b] != 0);
    } else {
      const float* mf = (const float*)mask;
      for (int i = t; i < LL; i += NTH) cnt += (mf[i * BB + b] != 0.f);
    }
    red[t] = (float)cnt;
    if (t < 64) red[192 + t] = 0.f;
    __syncthreads();
    for (int s = 128; s >= 1; s >>= 1) {
      if (t < s) red[t] += red[t + s];
      __syncthreads();
    }
    if (t == 0) len_sh = (int)(red[0] + 0.5f);
    __syncthreads();
  }
  const int len = len_sh;

  // ---- T2 = exp(trans): lane owns rows 24q..24q+23 of columns 2p, 2p+1 ----
  const float* tb = trans + (size_t)b * (CC * CC);
  float T2x[24], T2y[24];
#pragma unroll
  for (int j = 0; j < 24; ++j) {
    const float* row = tb + (q * 24 + j) * CC + 2 * p;
    T2x[j] = __expf(row[0]);
    T2y[j] = __expf(row[1]);
  }

  // ---- emit chunk prefetch pipeline: 192 thr stage 32x96 per chunk ----
  const int rw = t / 24;  // 0..7
  const int c4 = t % 24;  // float4 column
  const float4* e4 = (const float4*)emit;
  float4 rr[4];
#pragma unroll
  for (int u = 0; u < 4; ++u) {  // chunk 0 -> LDS now
    float4 v = e4[((rw + 8 * u) * BB + b) * 24 + c4];
    float4 o;
    o.x = __expf(v.x) * KAPPA; o.y = __expf(v.y) * KAPPA;
    o.z = __expf(v.z) * KAPPA; o.w = __expf(v.w) * KAPPA;
    *(float4*)&ebuf[0][rw + 8 * u][c4 * 4] = o;
  }
#pragma unroll
  for (int u = 0; u < 4; ++u)  // chunk 1 -> regs
    rr[u] = e4[((CHUNK + rw + 8 * u) * BB + b) * 24 + c4];

  // ---- init: u0 = exp(a0 - a0[0]), L = a0[0] ----
  float a00 = emit[(size_t)b * CC] + tstart[b * CC];
  float L = a00;
  if (t < CC) {
    float v = emit[(size_t)b * CC + t] + tstart[b * CC + t];
    p_lds[0][t] = __expf(v - a00);
  }
  __syncthreads();

  // ---- main recurrence: one barrier per step ----
  for (int i = 1; i < len; ++i) {
    if ((i & 31) == 0) {  // stage next chunk
      int ch = i >> 5;
      int es = ch & 1;
#pragma unroll
      for (int u = 0; u < 4; ++u) {
        float4 v = rr[u];
        float4 o;
        o.x = __expf(v.x) * KAPPA; o.y = __expf(v.y) * KAPPA;
        o.z = __expf(v.z) * KAPPA; o.w = __expf(v.w) * KAPPA;
        *(float4*)&ebuf[es][rw + 8 * u][c4 * 4] = o;
      }
      __syncthreads();
      int nb = (ch + 1) * CHUNK;
      if (nb < LL) {
#pragma unroll
        for (int u = 0; u < 4; ++u)
          rr[u] = e4[((nb + rw + 8 * u) * BB + b) * 24 + c4];
      }
    }
    const int slot_r = (i + 1) & 1;
    const bool rn = (i & 3) == 0;  // renorm step
    float piv = 1.f, invP = 1.f;
    if (rn) {
      piv = p_lds[slot_r][0];
      invP = 1.0f / piv;
    }
    const float4* p4 = (const float4*)&p_lds[slot_r][q * 24];
    float ax0 = 0.f, ay0 = 0.f, ax1 = 0.f, ay1 = 0.f;
#pragma unroll
    for (int j4 = 0; j4 < 6; j4 += 2) {
      float4 v0 = p4[j4], v1 = p4[j4 + 1];
      int j = 4 * j4;
      ax0 += v0.x * T2x[j] + v0.y * T2x[j + 1] + v0.z * T2x[j + 2] + v0.w * T2x[j + 3];
      ay0 += v0.x * T2y[j] + v0.y * T2y[j + 1] + v0.z * T2y[j + 2] + v0.w * T2y[j + 3];
      ax1 += v1.x * T2x[j + 4] + v1.y * T2x[j + 5] + v1.z * T2x[j + 6] + v1.w * T2x[j + 7];
      ay1 += v1.x * T2y[j + 4] + v1.y * T2y[j + 5] + v1.z * T2y[j + 6] + v1.w * T2y[j + 7];
    }
    float ax = ax0 + ax1, ay = ay0 + ay1;
    ax += __shfl_xor(ax, 1); ay += __shfl_xor(ay, 1);
    ax += __shfl_xor(ax, 2); ay += __shfl_xor(ay, 2);
    if (q == 0) {
      const float* eb = &ebuf[(i >> 5) & 1][i & 31][2 * p];
      float2 res;
      res.x = ax * eb[0] * invP;
      res.y = ay * eb[1] * invP;
      *(float2*)&p_lds[i & 1][2 * p] = res;
    }
    if (rn) L += __logf(piv);  // uniform across threads
    __syncthreads();
  }

  // ---- log Z ----
  const int fs = (len - 1) & 1;
  red[t] = (t < CC) ? p_lds[fs][t] * __expf(tend[b * CC + t]) : 0.f;
  if (t < 64) red[192 + t] = 0.f;
  __syncthreads();
  for (int s = 128; s >= 1; s >>= 1) {
    if (t < s) red[t] += red[t + s];
    __syncthreads();
  }
  if (t == 0)
    logz_sh = L + (float)(len - 1) * NEG_LOG_KAPPA + __logf(red[0]);
  __syncthreads();

  // ---- gold-path score ----
  float sc = 0.f;
  for (int i = t; i < len; i += NTH) {
    int tg = target[i * BB + b];
    sc += emit[((size_t)i * BB + b) * CC + tg];
    if (i >= 1) {
      int tp = target[(i - 1) * BB + b];
      sc += tb[tp * CC + tg];
    }
  }
  red[t] = sc;
  if (t < 64) red[192 + t] = 0.f;
  __syncthreads();
  for (int s = 128; s >= 1; s >>= 1) {
    if (t < s) red[t] += red[t + s];
    __syncthreads();
  }
  if (t == 0) {
    int tg0 = target[b];
    int tgl = target[(len - 1) * BB + b];
    float score = red[0] + tstart[b * CC + tg0] + tend[b * CC + tgl];
    atomicAdd(out, (logz_sh - score) * (1.0f / 256.0f));
  }
}

extern "C" void kernel_launch(void* const* d_in, const int* in_sizes, int n_in,
                              void* d_out, int out_size, void* d_ws, size_t ws_size,
                              hipStream_t stream) {
  const float* emit = (const float*)d_in[0];
  const float* hidden = (const float*)d_in[1];
  const int* target = (const int*)d_in[2];
  const void* mask = d_in[3];
  const float* Wt = (const float*)d_in[4];
  const float* bt = (const float*)d_in[5];
  const float* Ws = (const float*)d_in[6];
  const float* bs = (const float*)d_in[7];
  const float* We = (const float*)d_in[8];
  const float* be = (const float*)d_in[9];

  float* trans_ws = (float*)d_ws;                  // 256*9216
  float* ts_ws = trans_ws + (size_t)BB * CC * CC;  // 256*96
  float* te_ws = ts_ws + (size_t)BB * CC;          // 256*96

  hipMemsetAsync(d_out, 0, sizeof(float), stream);

  gemm_mfma<<<dim3((NTOT + 127) / 128, 2), 256, 0, stream>>>(
      hidden, Wt, Ws, We, bt, bs, be, trans_ws, ts_ws, te_ws);

  crf_scan<<<BB, NTH, 0, stream>>>(emit, target, mask, trans_ws, ts_ws, te_ws,
                                   (float*)d_out);
}